// Round 3
// baseline (1168.403 us; speedup 1.0000x reference)
//
#include <hip/hip_runtime.h>
#include <hip/hip_bf16.h>
#include <hip/hip_fp16.h>

#define BD 4
#define SS 4096
#define DD 1024
#define RTOT (BD*SS)   // 16384 total rows

typedef _Float16 f16;
typedef __attribute__((ext_vector_type(8))) _Float16 f16x8;
typedef __attribute__((ext_vector_type(8))) short bf16x8;
typedef __attribute__((ext_vector_type(4))) float f32x4;

static __device__ __forceinline__ unsigned short f2bf(float f) {
  unsigned int u = __float_as_uint(f);
  u += 0x7fff + ((u >> 16) & 1);   // RNE
  return (unsigned short)(u >> 16);
}
static __device__ __forceinline__ float bf2f(unsigned short h) {
  return __uint_as_float(((unsigned int)h) << 16);
}
static __device__ __forceinline__ unsigned short f2h(float f) {
  f16 h = (f16)f;
  return __builtin_bit_cast(unsigned short, h);
}

// async global->LDS, 16B/lane, wave-uniform LDS base + lane*16
static __device__ __forceinline__ void gload16(const void* g, void* l) {
  __builtin_amdgcn_global_load_lds(
      (const __attribute__((address_space(1))) unsigned int*)g,
      (__attribute__((address_space(3))) unsigned int*)l, 16, 0, 0);
}

// ---------------- split W into hi/lo bf16 ----------------
__global__ void split_w_kernel(const float* __restrict__ W,
                               unsigned short* __restrict__ Whi,
                               unsigned short* __restrict__ Wlo) {
  int i = (blockIdx.x * 256 + threadIdx.x) * 4;
  float4 x = *reinterpret_cast<const float4*>(W + i);
  ushort4 h, l;
  h.x = f2bf(x.x); l.x = f2bf(x.x - bf2f(h.x));
  h.y = f2bf(x.y); l.y = f2bf(x.y - bf2f(h.y));
  h.z = f2bf(x.z); l.z = f2bf(x.z - bf2f(h.z));
  h.w = f2bf(x.w); l.w = f2bf(x.w - bf2f(h.w));
  *reinterpret_cast<ushort4*>(Whi + i) = h;
  *reinterpret_cast<ushort4*>(Wlo + i) = l;
}

// ---------------- q/k projection: P = X W^T + b, bf16 3-term, hi/lo out ----------------
__global__ __launch_bounds__(256)
void proj_qk(const float* __restrict__ X,
             const unsigned short* __restrict__ Wh,
             const unsigned short* __restrict__ Wl,
             const float* __restrict__ bias,
             unsigned short* __restrict__ Ohi,
             unsigned short* __restrict__ Olo)
{
  __shared__ unsigned short Ah[128][40], Al[128][40];   // padded, reg-staged cvt
  __shared__ unsigned short Bh[128][32], Bl[128][32];   // linear, gload_lds
  const int tid = threadIdx.x, lane = tid & 63, wid = tid >> 6;
  const int m0 = blockIdx.x * 128, n0 = blockIdx.y * 128;
  const int wm = (wid >> 1) * 64, wn = (wid & 1) * 64;

  f32x4 acc[4][4] = {};

  for (int k0 = 0; k0 < DD; k0 += 32) {
    __syncthreads();
    // stage A: 128x32 fp32 -> hi/lo bf16
#pragma unroll
    for (int rnd = 0; rnd < 4; ++rnd) {
      int e = rnd * 256 + tid;
      int r = e >> 3, c = (e & 7) * 4;
      float4 x = *reinterpret_cast<const float4*>(X + (size_t)(m0 + r) * DD + k0 + c);
      ushort4 h, l;
      h.x = f2bf(x.x); l.x = f2bf(x.x - bf2f(h.x));
      h.y = f2bf(x.y); l.y = f2bf(x.y - bf2f(h.y));
      h.z = f2bf(x.z); l.z = f2bf(x.z - bf2f(h.z));
      h.w = f2bf(x.w); l.w = f2bf(x.w - bf2f(h.w));
      *reinterpret_cast<ushort4*>(&Ah[r][c]) = h;
      *reinterpret_cast<ushort4*>(&Al[r][c]) = l;
    }
    // stage B: pre-split W tiles via gload_lds
#pragma unroll
    for (int rnd = 0; rnd < 2; ++rnd) {
      int e = rnd * 256 + tid;
      size_t go = (size_t)(n0 + (e >> 2)) * DD + k0 + (e & 3) * 8;
      gload16(Wh + go, &Bh[0][0] + (size_t)e * 8);
      gload16(Wl + go, &Bl[0][0] + (size_t)e * 8);
    }
    __syncthreads();

    bf16x8 ah[4], al[4], bh[4], bl[4];
    const int fr = lane & 15, kb = (lane >> 4) * 8;
#pragma unroll
    for (int i = 0; i < 4; ++i) {
      ah[i] = *reinterpret_cast<const bf16x8*>(&Ah[wm + i * 16 + fr][kb]);
      al[i] = *reinterpret_cast<const bf16x8*>(&Al[wm + i * 16 + fr][kb]);
      bh[i] = *reinterpret_cast<const bf16x8*>(&Bh[wn + i * 16 + fr][kb]);
      bl[i] = *reinterpret_cast<const bf16x8*>(&Bl[wn + i * 16 + fr][kb]);
    }
#pragma unroll
    for (int i = 0; i < 4; ++i)
#pragma unroll
      for (int j = 0; j < 4; ++j) {
        acc[i][j] = __builtin_amdgcn_mfma_f32_16x16x32_bf16(ah[i], bh[j], acc[i][j], 0, 0, 0);
        acc[i][j] = __builtin_amdgcn_mfma_f32_16x16x32_bf16(ah[i], bl[j], acc[i][j], 0, 0, 0);
        acc[i][j] = __builtin_amdgcn_mfma_f32_16x16x32_bf16(al[i], bh[j], acc[i][j], 0, 0, 0);
      }
  }

  const int col = lane & 15, rb = (lane >> 4) * 4;
#pragma unroll
  for (int i = 0; i < 4; ++i)
#pragma unroll
    for (int j = 0; j < 4; ++j) {
      int oc = n0 + wn + j * 16 + col;
      float bv = bias[oc];
#pragma unroll
      for (int q = 0; q < 4; ++q) {
        int row = m0 + wm + i * 16 + rb + q;
        float p = acc[i][j][q] + bv;
        unsigned short h = f2bf(p);
        Ohi[(size_t)row * DD + oc] = h;
        Olo[(size_t)row * DD + oc] = f2bf(p - bf2f(h));
      }
    }
}

// ---------------- v projection: single-term bf16, writes v^T f16 [b][o][s] ----------------
__global__ __launch_bounds__(256)
void proj_v(const float* __restrict__ X,
            const unsigned short* __restrict__ Wh,
            const float* __restrict__ bias,
            unsigned short* __restrict__ vT)
{
  __shared__ unsigned short As[128][40];   // padded, reg-staged cvt
  __shared__ unsigned short Bs[128][32];   // linear, gload_lds
  const int tid = threadIdx.x, lane = tid & 63, wid = tid >> 6;
  const int m0 = blockIdx.x * 128, n0 = blockIdx.y * 128;
  const int wm = (wid >> 1) * 64, wn = (wid & 1) * 64;

  f32x4 acc[4][4] = {};

  for (int k0 = 0; k0 < DD; k0 += 32) {
    __syncthreads();
#pragma unroll
    for (int rnd = 0; rnd < 4; ++rnd) {
      int e = rnd * 256 + tid;
      int r = e >> 3, c = (e & 7) * 4;
      float4 x = *reinterpret_cast<const float4*>(X + (size_t)(m0 + r) * DD + k0 + c);
      ushort4 h;
      h.x = f2bf(x.x); h.y = f2bf(x.y); h.z = f2bf(x.z); h.w = f2bf(x.w);
      *reinterpret_cast<ushort4*>(&As[r][c]) = h;
    }
#pragma unroll
    for (int rnd = 0; rnd < 2; ++rnd) {
      int e = rnd * 256 + tid;
      gload16(Wh + (size_t)(n0 + (e >> 2)) * DD + k0 + (e & 3) * 8,
              &Bs[0][0] + (size_t)e * 8);
    }
    __syncthreads();

    bf16x8 a[4], b[4];
    const int fr = lane & 15, kb = (lane >> 4) * 8;
#pragma unroll
    for (int i = 0; i < 4; ++i) {
      a[i] = *reinterpret_cast<const bf16x8*>(&As[wm + i * 16 + fr][kb]);
      b[i] = *reinterpret_cast<const bf16x8*>(&Bs[wn + i * 16 + fr][kb]);
    }
#pragma unroll
    for (int i = 0; i < 4; ++i)
#pragma unroll
      for (int j = 0; j < 4; ++j)
        acc[i][j] = __builtin_amdgcn_mfma_f32_16x16x32_bf16(a[i], b[j], acc[i][j], 0, 0, 0);
  }

  const int col = lane & 15, rb = (lane >> 4) * 4;
#pragma unroll
  for (int i = 0; i < 4; ++i)
#pragma unroll
    for (int j = 0; j < 4; ++j) {
      int oc = n0 + wn + j * 16 + col;
      float bv = bias[oc];
      int row = m0 + wm + i * 16 + rb;     // 4 consecutive s
      int bb = row >> 12, s = row & (SS - 1);
      ushort4 h;
      h.x = f2h(acc[i][j][0] + bv);
      h.y = f2h(acc[i][j][1] + bv);
      h.z = f2h(acc[i][j][2] + bv);
      h.w = f2h(acc[i][j][3] + bv);
      *reinterpret_cast<ushort4*>(vT + ((size_t)(bb * DD + oc)) * SS + s) = h;
    }
}

// ---------------- logits: A[b,t,s] = q.k, bf16 3-term, gload_lds + XCD swizzle ----------------
__global__ __launch_bounds__(256)
void logits_bf3(const unsigned short* __restrict__ qh, const unsigned short* __restrict__ ql,
                const unsigned short* __restrict__ kh, const unsigned short* __restrict__ kl,
                float* __restrict__ out)
{
  __shared__ unsigned short Qh[128][32], Ql[128][32], Kh[128][32], Kl[128][32];
  const int tid = threadIdx.x, lane = tid & 63, wid = tid >> 6;
  // XCD-aware swizzle: 4096 blocks, 8 XCDs, 512 contiguous per XCD
  int id = blockIdx.x;
  int nid = (id & 7) * 512 + (id >> 3);
  int b = nid >> 10, r2 = nid & 1023;
  int t0 = (r2 >> 5) * 128, s0 = (r2 & 31) * 128;
  const unsigned short* qhB = qh + ((size_t)b * SS + t0) * DD;
  const unsigned short* qlB = ql + ((size_t)b * SS + t0) * DD;
  const unsigned short* khB = kh + ((size_t)b * SS + s0) * DD;
  const unsigned short* klB = kl + ((size_t)b * SS + s0) * DD;
  const int wm = (wid >> 1) * 64, wn = (wid & 1) * 64;

  f32x4 acc[4][4] = {};

  for (int k0 = 0; k0 < DD; k0 += 32) {
    __syncthreads();
#pragma unroll
    for (int rnd = 0; rnd < 2; ++rnd) {
      int e = rnd * 256 + tid;
      size_t go = (size_t)(e >> 2) * DD + k0 + (e & 3) * 8;
      size_t lo = (size_t)e * 8;
      gload16(qhB + go, &Qh[0][0] + lo);
      gload16(qlB + go, &Ql[0][0] + lo);
      gload16(khB + go, &Kh[0][0] + lo);
      gload16(klB + go, &Kl[0][0] + lo);
    }
    __syncthreads();

    bf16x8 ah[4], al[4], bh[4], bl[4];
    const int fr = lane & 15, kb = (lane >> 4) * 8;
#pragma unroll
    for (int i = 0; i < 4; ++i) {
      ah[i] = *reinterpret_cast<const bf16x8*>(&Qh[wm + i * 16 + fr][kb]);
      al[i] = *reinterpret_cast<const bf16x8*>(&Ql[wm + i * 16 + fr][kb]);
      bh[i] = *reinterpret_cast<const bf16x8*>(&Kh[wn + i * 16 + fr][kb]);
      bl[i] = *reinterpret_cast<const bf16x8*>(&Kl[wn + i * 16 + fr][kb]);
    }
#pragma unroll
    for (int i = 0; i < 4; ++i)
#pragma unroll
      for (int j = 0; j < 4; ++j) {
        acc[i][j] = __builtin_amdgcn_mfma_f32_16x16x32_bf16(ah[i], bh[j], acc[i][j], 0, 0, 0);
        acc[i][j] = __builtin_amdgcn_mfma_f32_16x16x32_bf16(ah[i], bl[j], acc[i][j], 0, 0, 0);
        acc[i][j] = __builtin_amdgcn_mfma_f32_16x16x32_bf16(al[i], bh[j], acc[i][j], 0, 0, 0);
      }
  }

  const int col = lane & 15, rb = (lane >> 4) * 4;
#pragma unroll
  for (int i = 0; i < 4; ++i)
#pragma unroll
    for (int j = 0; j < 4; ++j) {
      int s = s0 + wn + j * 16 + col;
#pragma unroll
      for (int q = 0; q < 4; ++q) {
        int t = t0 + wm + i * 16 + rb + q;
        out[((size_t)b * SS + t) * SS + s] = acc[i][j][q];
      }
    }
}

// ---------------- row softmax in-place ----------------
__global__ __launch_bounds__(256)
void softmax_kernel(float* __restrict__ attn) {
  float* rp = attn + (size_t)blockIdx.x * SS;
  const int tid = threadIdx.x, lane = tid & 63, wid = tid >> 6;
  float v[16];
  float m = -1e30f;
#pragma unroll
  for (int i = 0; i < 4; ++i) {
    float4 x = *reinterpret_cast<const float4*>(rp + i * 1024 + tid * 4);
    v[i * 4 + 0] = x.x; v[i * 4 + 1] = x.y; v[i * 4 + 2] = x.z; v[i * 4 + 3] = x.w;
    m = fmaxf(m, fmaxf(fmaxf(x.x, x.y), fmaxf(x.z, x.w)));
  }
#pragma unroll
  for (int off = 32; off; off >>= 1) m = fmaxf(m, __shfl_xor(m, off));
  __shared__ float redm[4], reds[4];
  if (lane == 0) redm[wid] = m;
  __syncthreads();
  m = fmaxf(fmaxf(redm[0], redm[1]), fmaxf(redm[2], redm[3]));
  float sum = 0.f;
#pragma unroll
  for (int i = 0; i < 16; ++i) { v[i] = __expf(v[i] - m); sum += v[i]; }
#pragma unroll
  for (int off = 32; off; off >>= 1) sum += __shfl_xor(sum, off);
  if (lane == 0) reds[wid] = sum;
  __syncthreads();
  float inv = 1.0f / (reds[0] + reds[1] + reds[2] + reds[3]);
#pragma unroll
  for (int i = 0; i < 4; ++i) {
    float4 x;
    x.x = v[i * 4 + 0] * inv; x.y = v[i * 4 + 1] * inv;
    x.z = v[i * 4 + 2] * inv; x.w = v[i * 4 + 3] * inv;
    *reinterpret_cast<float4*>(rp + i * 1024 + tid * 4) = x;
  }
}

// ---------------- PV GEMM: O[b,t,o] = sum_s attn[t,s] v[s,o] (f16) ----------------
__global__ __launch_bounds__(256)
void pv_f16(const float* __restrict__ attn, const unsigned short* __restrict__ vT,
            float* __restrict__ out)
{
  __shared__ unsigned short As[128][40];   // padded, fp32->f16 cvt staging
  __shared__ unsigned short Bs[128][32];   // linear, gload_lds
  const int tid = threadIdx.x, lane = tid & 63, wid = tid >> 6;
  const int b = blockIdx.z, t0 = blockIdx.x * 128, n0 = blockIdx.y * 128;
  const float* aB = attn + (size_t)b * SS * SS;
  const unsigned short* vB = vT + ((size_t)b * DD + n0) * SS;
  const int wm = (wid >> 1) * 64, wn = (wid & 1) * 64;

  f32x4 acc[4][4] = {};

  for (int s0 = 0; s0 < SS; s0 += 32) {
    __syncthreads();
#pragma unroll
    for (int rnd = 0; rnd < 4; ++rnd) {
      int e = rnd * 256 + tid;
      int r = e >> 3, c = (e & 7) * 4;
      float4 x = *reinterpret_cast<const float4*>(aB + (size_t)(t0 + r) * SS + s0 + c);
      ushort4 h;
      h.x = f2h(x.x); h.y = f2h(x.y); h.z = f2h(x.z); h.w = f2h(x.w);
      *reinterpret_cast<ushort4*>(&As[r][c]) = h;
    }
#pragma unroll
    for (int rnd = 0; rnd < 2; ++rnd) {
      int e = rnd * 256 + tid;
      gload16(vB + (size_t)(e >> 2) * SS + s0 + (e & 3) * 8, &Bs[0][0] + (size_t)e * 8);
    }
    __syncthreads();

    f16x8 a[4], b4[4];
    const int fr = lane & 15, kb = (lane >> 4) * 8;
#pragma unroll
    for (int i = 0; i < 4; ++i) {
      a[i]  = *reinterpret_cast<const f16x8*>(&As[wm + i * 16 + fr][kb]);
      b4[i] = *reinterpret_cast<const f16x8*>(&Bs[wn + i * 16 + fr][kb]);
    }
#pragma unroll
    for (int i = 0; i < 4; ++i)
#pragma unroll
      for (int j = 0; j < 4; ++j)
        acc[i][j] = __builtin_amdgcn_mfma_f32_16x16x32_f16(a[i], b4[j], acc[i][j], 0, 0, 0);
  }

  const int col = lane & 15, rb = (lane >> 4) * 4;
#pragma unroll
  for (int i = 0; i < 4; ++i)
#pragma unroll
    for (int j = 0; j < 4; ++j) {
      int o = n0 + wn + j * 16 + col;
#pragma unroll
      for (int q = 0; q < 4; ++q) {
        int t = t0 + wm + i * 16 + rb + q;
        out[((size_t)b * SS + t) * DD + o] = acc[i][j][q];
      }
    }
}

extern "C" void kernel_launch(void* const* d_in, const int* in_sizes, int n_in,
                              void* d_out, int out_size, void* d_ws, size_t ws_size,
                              hipStream_t stream) {
  const float* query = (const float*)d_in[0];
  const float* key   = (const float*)d_in[1];
  const float* value = (const float*)d_in[2];
  const float* W     = (const float*)d_in[3];
  const float* bias  = (const float*)d_in[4];

  float* out  = (float*)d_out;                  // [B,S,D]
  float* attn = out + (size_t)BD * SS * DD;     // [B,S,S]

  // workspace: Whi/Wlo 4MB + q/k hi/lo 134MB + vT 33.5MB = 171.5MB (same as R1)
  unsigned short* Whi = (unsigned short*)d_ws;
  unsigned short* Wlo = Whi + (size_t)DD * DD;
  unsigned short* qhi = Wlo + (size_t)DD * DD;
  unsigned short* qlo = qhi + (size_t)RTOT * DD;
  unsigned short* khi = qlo + (size_t)RTOT * DD;
  unsigned short* klo = khi + (size_t)RTOT * DD;
  unsigned short* vT  = klo + (size_t)RTOT * DD;

  split_w_kernel<<<DD * DD / (256 * 4), 256, 0, stream>>>(W, Whi, Wlo);

  dim3 gp(RTOT / 128, DD / 128);
  proj_qk<<<gp, 256, 0, stream>>>(query, Whi, Wlo, bias, qhi, qlo);
  proj_qk<<<gp, 256, 0, stream>>>(key,   Whi, Wlo, bias, khi, klo);
  proj_v <<<gp, 256, 0, stream>>>(value, Whi, bias, vT);

  logits_bf3<<<SS / 128 * SS / 128 * BD, 256, 0, stream>>>(qhi, qlo, khi, klo, attn);
  softmax_kernel<<<RTOT, 256, 0, stream>>>(attn);
  pv_f16<<<dim3(SS / 128, DD / 128, BD), 256, 0, stream>>>(attn, vT, out);
}

// Round 4
// 1058.090 us; speedup vs baseline: 1.1043x; 1.1043x over previous
//
#include <hip/hip_runtime.h>
#include <hip/hip_bf16.h>
#include <hip/hip_fp16.h>

#define BD 4
#define SS 4096
#define DD 1024
#define RTOT (BD*SS)   // 16384 total rows

typedef _Float16 f16;
typedef __attribute__((ext_vector_type(8))) _Float16 f16x8;
typedef __attribute__((ext_vector_type(8))) short bf16x8;
typedef __attribute__((ext_vector_type(4))) float f32x4;

static __device__ __forceinline__ unsigned short f2bf(float f) {
  unsigned int u = __float_as_uint(f);
  u += 0x7fff + ((u >> 16) & 1);   // RNE
  return (unsigned short)(u >> 16);
}
static __device__ __forceinline__ float bf2f(unsigned short h) {
  return __uint_as_float(((unsigned int)h) << 16);
}
static __device__ __forceinline__ unsigned short f2h(float f) {
  f16 h = (f16)f;
  return __builtin_bit_cast(unsigned short, h);
}

// async global->LDS, 16B/lane, wave-uniform LDS base + lane*16
static __device__ __forceinline__ void gload16(const void* g, void* l) {
  __builtin_amdgcn_global_load_lds(
      (const __attribute__((address_space(1))) unsigned int*)g,
      (__attribute__((address_space(3))) unsigned int*)l, 16, 0, 0);
}

// ---------------- split W into hi/lo bf16 ----------------
__global__ void split_w_kernel(const float* __restrict__ W,
                               unsigned short* __restrict__ Whi,
                               unsigned short* __restrict__ Wlo) {
  int i = (blockIdx.x * 256 + threadIdx.x) * 4;
  float4 x = *reinterpret_cast<const float4*>(W + i);
  ushort4 h, l;
  h.x = f2bf(x.x); l.x = f2bf(x.x - bf2f(h.x));
  h.y = f2bf(x.y); l.y = f2bf(x.y - bf2f(h.y));
  h.z = f2bf(x.z); l.z = f2bf(x.z - bf2f(h.z));
  h.w = f2bf(x.w); l.w = f2bf(x.w - bf2f(h.w));
  *reinterpret_cast<ushort4*>(Whi + i) = h;
  *reinterpret_cast<ushort4*>(Wlo + i) = l;
}

// ---------------- q/k projection: P = X W^T + b, bf16 3-term, hi/lo out ----------------
__global__ __launch_bounds__(256)
void proj_qk(const float* __restrict__ X,
             const unsigned short* __restrict__ Wh,
             const unsigned short* __restrict__ Wl,
             const float* __restrict__ bias,
             unsigned short* __restrict__ Ohi,
             unsigned short* __restrict__ Olo)
{
  __shared__ unsigned short Ah[128][40], Al[128][40];   // padded, reg-staged cvt
  __shared__ unsigned short Bh[128][32], Bl[128][32];   // linear, gload_lds
  const int tid = threadIdx.x, lane = tid & 63, wid = tid >> 6;
  const int m0 = blockIdx.x * 128, n0 = blockIdx.y * 128;
  const int wm = (wid >> 1) * 64, wn = (wid & 1) * 64;

  f32x4 acc[4][4] = {};

  for (int k0 = 0; k0 < DD; k0 += 32) {
    __syncthreads();
#pragma unroll
    for (int rnd = 0; rnd < 4; ++rnd) {
      int e = rnd * 256 + tid;
      int r = e >> 3, c = (e & 7) * 4;
      float4 x = *reinterpret_cast<const float4*>(X + (size_t)(m0 + r) * DD + k0 + c);
      ushort4 h, l;
      h.x = f2bf(x.x); l.x = f2bf(x.x - bf2f(h.x));
      h.y = f2bf(x.y); l.y = f2bf(x.y - bf2f(h.y));
      h.z = f2bf(x.z); l.z = f2bf(x.z - bf2f(h.z));
      h.w = f2bf(x.w); l.w = f2bf(x.w - bf2f(h.w));
      *reinterpret_cast<ushort4*>(&Ah[r][c]) = h;
      *reinterpret_cast<ushort4*>(&Al[r][c]) = l;
    }
#pragma unroll
    for (int rnd = 0; rnd < 2; ++rnd) {
      int e = rnd * 256 + tid;
      size_t go = (size_t)(n0 + (e >> 2)) * DD + k0 + (e & 3) * 8;
      gload16(Wh + go, &Bh[0][0] + (size_t)e * 8);
      gload16(Wl + go, &Bl[0][0] + (size_t)e * 8);
    }
    __syncthreads();

    bf16x8 ah[4], al[4], bh[4], bl[4];
    const int fr = lane & 15, kb = (lane >> 4) * 8;
#pragma unroll
    for (int i = 0; i < 4; ++i) {
      ah[i] = *reinterpret_cast<const bf16x8*>(&Ah[wm + i * 16 + fr][kb]);
      al[i] = *reinterpret_cast<const bf16x8*>(&Al[wm + i * 16 + fr][kb]);
      bh[i] = *reinterpret_cast<const bf16x8*>(&Bh[wn + i * 16 + fr][kb]);
      bl[i] = *reinterpret_cast<const bf16x8*>(&Bl[wn + i * 16 + fr][kb]);
    }
#pragma unroll
    for (int i = 0; i < 4; ++i)
#pragma unroll
      for (int j = 0; j < 4; ++j) {
        acc[i][j] = __builtin_amdgcn_mfma_f32_16x16x32_bf16(ah[i], bh[j], acc[i][j], 0, 0, 0);
        acc[i][j] = __builtin_amdgcn_mfma_f32_16x16x32_bf16(ah[i], bl[j], acc[i][j], 0, 0, 0);
        acc[i][j] = __builtin_amdgcn_mfma_f32_16x16x32_bf16(al[i], bh[j], acc[i][j], 0, 0, 0);
      }
  }

  const int col = lane & 15, rb = (lane >> 4) * 4;
#pragma unroll
  for (int i = 0; i < 4; ++i)
#pragma unroll
    for (int j = 0; j < 4; ++j) {
      int oc = n0 + wn + j * 16 + col;
      float bv = bias[oc];
#pragma unroll
      for (int q = 0; q < 4; ++q) {
        int row = m0 + wm + i * 16 + rb + q;
        float p = acc[i][j][q] + bv;
        unsigned short h = f2bf(p);
        Ohi[(size_t)row * DD + oc] = h;
        Olo[(size_t)row * DD + oc] = f2bf(p - bf2f(h));
      }
    }
}

// ---------------- v projection: single-term bf16, writes v^T f16 [b][o][s] ----------------
__global__ __launch_bounds__(256)
void proj_v(const float* __restrict__ X,
            const unsigned short* __restrict__ Wh,
            const float* __restrict__ bias,
            unsigned short* __restrict__ vT)
{
  __shared__ unsigned short As[128][40];
  __shared__ unsigned short Bs[128][32];
  const int tid = threadIdx.x, lane = tid & 63, wid = tid >> 6;
  const int m0 = blockIdx.x * 128, n0 = blockIdx.y * 128;
  const int wm = (wid >> 1) * 64, wn = (wid & 1) * 64;

  f32x4 acc[4][4] = {};

  for (int k0 = 0; k0 < DD; k0 += 32) {
    __syncthreads();
#pragma unroll
    for (int rnd = 0; rnd < 4; ++rnd) {
      int e = rnd * 256 + tid;
      int r = e >> 3, c = (e & 7) * 4;
      float4 x = *reinterpret_cast<const float4*>(X + (size_t)(m0 + r) * DD + k0 + c);
      ushort4 h;
      h.x = f2bf(x.x); h.y = f2bf(x.y); h.z = f2bf(x.z); h.w = f2bf(x.w);
      *reinterpret_cast<ushort4*>(&As[r][c]) = h;
    }
#pragma unroll
    for (int rnd = 0; rnd < 2; ++rnd) {
      int e = rnd * 256 + tid;
      gload16(Wh + (size_t)(n0 + (e >> 2)) * DD + k0 + (e & 3) * 8,
              &Bs[0][0] + (size_t)e * 8);
    }
    __syncthreads();

    bf16x8 a[4], b[4];
    const int fr = lane & 15, kb = (lane >> 4) * 8;
#pragma unroll
    for (int i = 0; i < 4; ++i) {
      a[i] = *reinterpret_cast<const bf16x8*>(&As[wm + i * 16 + fr][kb]);
      b[i] = *reinterpret_cast<const bf16x8*>(&Bs[wn + i * 16 + fr][kb]);
    }
#pragma unroll
    for (int i = 0; i < 4; ++i)
#pragma unroll
      for (int j = 0; j < 4; ++j)
        acc[i][j] = __builtin_amdgcn_mfma_f32_16x16x32_bf16(a[i], b[j], acc[i][j], 0, 0, 0);
  }

  const int col = lane & 15, rb = (lane >> 4) * 4;
#pragma unroll
  for (int i = 0; i < 4; ++i)
#pragma unroll
    for (int j = 0; j < 4; ++j) {
      int oc = n0 + wn + j * 16 + col;
      float bv = bias[oc];
      int row = m0 + wm + i * 16 + rb;
      int bb = row >> 12, s = row & (SS - 1);
      ushort4 h;
      h.x = f2h(acc[i][j][0] + bv);
      h.y = f2h(acc[i][j][1] + bv);
      h.z = f2h(acc[i][j][2] + bv);
      h.w = f2h(acc[i][j][3] + bv);
      *reinterpret_cast<ushort4*>(vT + ((size_t)(bb * DD + oc)) * SS + s) = h;
    }
}

// ---------------- logits v2: 256x256 tile, 8 waves, BK=32, dbuf, swizzled LDS ----------------
// LDS: 8 buffers x 16KB = 128 KiB. buf layout per operand: 16 regions (16 rows) x 64
// granules (16B). Granule within region: g = fr*4 + (cc ^ ((fr>>1)&3))  [conflict-free]
__global__ __launch_bounds__(512, 2)
void logits_v2(const unsigned short* __restrict__ qh, const unsigned short* __restrict__ ql,
               const unsigned short* __restrict__ kh, const unsigned short* __restrict__ kl,
               float* __restrict__ out)
{
  __shared__ unsigned short lds[8][8192];   // [dbuf*4 ops][16KB each]
  const int tid = threadIdx.x, lane = tid & 63, wid = tid >> 6;

  // bijective XCD swizzle: 1024 blocks % 8 == 0
  int bid = blockIdx.x;
  int swz = (bid & 7) * 128 + (bid >> 3);
  const int b = swz >> 8;
  const int r = swz & 255;
  const int t0 = (r >> 4) * 256, s0 = (r & 15) * 256;

  const unsigned short* qhB = qh + (size_t)b * SS * DD;
  const unsigned short* qlB = ql + (size_t)b * SS * DD;
  const unsigned short* khB = kh + (size_t)b * SS * DD;
  const unsigned short* klB = kl + (size_t)b * SS * DD;

  // ---- stage address precompute (per thread): granule G0 = tid, G1 = 512+tid
  // fr/cs identical for both rounds; row differs by +128
  const int sfr = (tid >> 2) & 15;
  const int scc = (tid & 3) ^ ((sfr >> 1) & 3);
  const int srowl = (tid >> 6) * 16 + sfr;
  const size_t qoff0 = (size_t)(t0 + srowl) * DD + scc * 8;
  const size_t koff0 = (size_t)(s0 + srowl) * DD + scc * 8;
  const int l0s = tid * 8;          // LDS short index, round 0
  const int l1s = 4096 + tid * 8;   // round 1 (+128 rows)

#define STAGE(cur, k0)  do { \
    gload16(qhB + qoff0 + (k0),          &lds[(cur)*4+0][l0s]); \
    gload16(qhB + qoff0 + 131072 + (k0), &lds[(cur)*4+0][l1s]); \
    gload16(qlB + qoff0 + (k0),          &lds[(cur)*4+1][l0s]); \
    gload16(qlB + qoff0 + 131072 + (k0), &lds[(cur)*4+1][l1s]); \
    gload16(khB + koff0 + (k0),          &lds[(cur)*4+2][l0s]); \
    gload16(khB + koff0 + 131072 + (k0), &lds[(cur)*4+2][l1s]); \
    gload16(klB + koff0 + (k0),          &lds[(cur)*4+3][l0s]); \
    gload16(klB + koff0 + 131072 + (k0), &lds[(cur)*4+3][l1s]); \
  } while (0)

  // ---- wave tiling: 2(M) x 4(N); wave tile 128x64
  const int wr = wid >> 2, wc = wid & 3;
  // read lane-part granule offset (same involution as stage)
  const int rfr = lane & 15, rcc = lane >> 4;
  const int lp8 = (rfr * 4 + (rcc ^ ((rfr >> 1) & 3))) * 8;   // short index within region

  f32x4 acc[8][4] = {};

  int cur = 0;
  STAGE(0, 0);
  __syncthreads();

  for (int t = 0; t < 32; ++t) {
    if (t < 31) STAGE(cur ^ 1, (t + 1) * 32);

    bf16x8 bhf[4], blf[4];
#pragma unroll
    for (int n = 0; n < 4; ++n) {
      bhf[n] = *reinterpret_cast<const bf16x8*>(&lds[cur * 4 + 2][(wc * 4 + n) * 512 + lp8]);
      blf[n] = *reinterpret_cast<const bf16x8*>(&lds[cur * 4 + 3][(wc * 4 + n) * 512 + lp8]);
    }
#pragma unroll
    for (int h = 0; h < 2; ++h) {
      bf16x8 ahf[4], alf[4];
#pragma unroll
      for (int m = 0; m < 4; ++m) {
        ahf[m] = *reinterpret_cast<const bf16x8*>(&lds[cur * 4 + 0][(wr * 8 + h * 4 + m) * 512 + lp8]);
        alf[m] = *reinterpret_cast<const bf16x8*>(&lds[cur * 4 + 1][(wr * 8 + h * 4 + m) * 512 + lp8]);
      }
      __builtin_amdgcn_s_setprio(1);
#pragma unroll
      for (int m = 0; m < 4; ++m)
#pragma unroll
        for (int n = 0; n < 4; ++n) {
          acc[h * 4 + m][n] = __builtin_amdgcn_mfma_f32_16x16x32_bf16(ahf[m], bhf[n], acc[h * 4 + m][n], 0, 0, 0);
          acc[h * 4 + m][n] = __builtin_amdgcn_mfma_f32_16x16x32_bf16(ahf[m], blf[n], acc[h * 4 + m][n], 0, 0, 0);
          acc[h * 4 + m][n] = __builtin_amdgcn_mfma_f32_16x16x32_bf16(alf[m], bhf[n], acc[h * 4 + m][n], 0, 0, 0);
        }
      __builtin_amdgcn_s_setprio(0);
    }
    __syncthreads();
    cur ^= 1;
  }
#undef STAGE

  const int col = lane & 15, rb = (lane >> 4) * 4;
#pragma unroll
  for (int m = 0; m < 8; ++m)
#pragma unroll
    for (int n = 0; n < 4; ++n) {
      int s = s0 + wc * 64 + n * 16 + col;
#pragma unroll
      for (int q = 0; q < 4; ++q) {
        int tr = t0 + wr * 128 + m * 16 + rb + q;
        out[((size_t)b * SS + tr) * SS + s] = acc[m][n][q];
      }
    }
}

// ---------------- row softmax in-place ----------------
__global__ __launch_bounds__(256)
void softmax_kernel(float* __restrict__ attn) {
  float* rp = attn + (size_t)blockIdx.x * SS;
  const int tid = threadIdx.x, lane = tid & 63, wid = tid >> 6;
  float v[16];
  float m = -1e30f;
#pragma unroll
  for (int i = 0; i < 4; ++i) {
    float4 x = *reinterpret_cast<const float4*>(rp + i * 1024 + tid * 4);
    v[i * 4 + 0] = x.x; v[i * 4 + 1] = x.y; v[i * 4 + 2] = x.z; v[i * 4 + 3] = x.w;
    m = fmaxf(m, fmaxf(fmaxf(x.x, x.y), fmaxf(x.z, x.w)));
  }
#pragma unroll
  for (int off = 32; off; off >>= 1) m = fmaxf(m, __shfl_xor(m, off));
  __shared__ float redm[4], reds[4];
  if (lane == 0) redm[wid] = m;
  __syncthreads();
  m = fmaxf(fmaxf(redm[0], redm[1]), fmaxf(redm[2], redm[3]));
  float sum = 0.f;
#pragma unroll
  for (int i = 0; i < 16; ++i) { v[i] = __expf(v[i] - m); sum += v[i]; }
#pragma unroll
  for (int off = 32; off; off >>= 1) sum += __shfl_xor(sum, off);
  if (lane == 0) reds[wid] = sum;
  __syncthreads();
  float inv = 1.0f / (reds[0] + reds[1] + reds[2] + reds[3]);
#pragma unroll
  for (int i = 0; i < 4; ++i) {
    float4 x;
    x.x = v[i * 4 + 0] * inv; x.y = v[i * 4 + 1] * inv;
    x.z = v[i * 4 + 2] * inv; x.w = v[i * 4 + 3] * inv;
    *reinterpret_cast<float4*>(rp + i * 1024 + tid * 4) = x;
  }
}

// ---------------- PV GEMM: O[b,t,o] = sum_s attn[t,s] v[s,o] (f16) ----------------
__global__ __launch_bounds__(256)
void pv_f16(const float* __restrict__ attn, const unsigned short* __restrict__ vT,
            float* __restrict__ out)
{
  __shared__ unsigned short As[128][40];
  __shared__ unsigned short Bs[128][32];
  const int tid = threadIdx.x, lane = tid & 63, wid = tid >> 6;
  const int b = blockIdx.z, t0 = blockIdx.x * 128, n0 = blockIdx.y * 128;
  const float* aB = attn + (size_t)b * SS * SS;
  const unsigned short* vB = vT + ((size_t)b * DD + n0) * SS;
  const int wm = (wid >> 1) * 64, wn = (wid & 1) * 64;

  f32x4 acc[4][4] = {};

  for (int s0 = 0; s0 < SS; s0 += 32) {
    __syncthreads();
#pragma unroll
    for (int rnd = 0; rnd < 4; ++rnd) {
      int e = rnd * 256 + tid;
      int r = e >> 3, c = (e & 7) * 4;
      float4 x = *reinterpret_cast<const float4*>(aB + (size_t)(t0 + r) * SS + s0 + c);
      ushort4 h;
      h.x = f2h(x.x); h.y = f2h(x.y); h.z = f2h(x.z); h.w = f2h(x.w);
      *reinterpret_cast<ushort4*>(&As[r][c]) = h;
    }
#pragma unroll
    for (int rnd = 0; rnd < 2; ++rnd) {
      int e = rnd * 256 + tid;
      gload16(vB + (size_t)(e >> 2) * SS + s0 + (e & 3) * 8, &Bs[0][0] + (size_t)e * 8);
    }
    __syncthreads();

    f16x8 a[4], b4[4];
    const int fr = lane & 15, kb = (lane >> 4) * 8;
#pragma unroll
    for (int i = 0; i < 4; ++i) {
      a[i]  = *reinterpret_cast<const f16x8*>(&As[wm + i * 16 + fr][kb]);
      b4[i] = *reinterpret_cast<const f16x8*>(&Bs[wn + i * 16 + fr][kb]);
    }
#pragma unroll
    for (int i = 0; i < 4; ++i)
#pragma unroll
      for (int j = 0; j < 4; ++j)
        acc[i][j] = __builtin_amdgcn_mfma_f32_16x16x32_f16(a[i], b4[j], acc[i][j], 0, 0, 0);
  }

  const int col = lane & 15, rb = (lane >> 4) * 4;
#pragma unroll
  for (int i = 0; i < 4; ++i)
#pragma unroll
    for (int j = 0; j < 4; ++j) {
      int o = n0 + wn + j * 16 + col;
#pragma unroll
      for (int q = 0; q < 4; ++q) {
        int t = t0 + wm + i * 16 + rb + q;
        out[((size_t)b * SS + t) * DD + o] = acc[i][j][q];
      }
    }
}

extern "C" void kernel_launch(void* const* d_in, const int* in_sizes, int n_in,
                              void* d_out, int out_size, void* d_ws, size_t ws_size,
                              hipStream_t stream) {
  const float* query = (const float*)d_in[0];
  const float* key   = (const float*)d_in[1];
  const float* value = (const float*)d_in[2];
  const float* W     = (const float*)d_in[3];
  const float* bias  = (const float*)d_in[4];

  float* out  = (float*)d_out;                  // [B,S,D]
  float* attn = out + (size_t)BD * SS * DD;     // [B,S,S]

  unsigned short* Whi = (unsigned short*)d_ws;
  unsigned short* Wlo = Whi + (size_t)DD * DD;
  unsigned short* qhi = Wlo + (size_t)DD * DD;
  unsigned short* qlo = qhi + (size_t)RTOT * DD;
  unsigned short* khi = qlo + (size_t)RTOT * DD;
  unsigned short* klo = khi + (size_t)RTOT * DD;
  unsigned short* vT  = klo + (size_t)RTOT * DD;

  split_w_kernel<<<DD * DD / (256 * 4), 256, 0, stream>>>(W, Whi, Wlo);

  dim3 gp(RTOT / 128, DD / 128);
  proj_qk<<<gp, 256, 0, stream>>>(query, Whi, Wlo, bias, qhi, qlo);
  proj_qk<<<gp, 256, 0, stream>>>(key,   Whi, Wlo, bias, khi, klo);
  proj_v <<<gp, 256, 0, stream>>>(value, Whi, bias, vT);

  logits_v2<<<(SS / 256) * (SS / 256) * BD, 512, 0, stream>>>(qhi, qlo, khi, klo, attn);
  softmax_kernel<<<RTOT, 256, 0, stream>>>(attn);
  pv_f16<<<dim3(SS / 128, DD / 128, BD), 256, 0, stream>>>(attn, vT, out);
}